// Round 11
// baseline (4420.267 us; speedup 1.0000x reference)
//
#include <hip/hip_runtime.h>
#include <hip/hip_fp16.h>
#include <stdint.h>

#define D 128
#define NUM_HOPS 8
#define FILLA_EPT 16   // edges per thread in binning kernels (4096/wg)

typedef float f32x2 __attribute__((ext_vector_type(2)));

// ---------------- Threefry-2x32 (matches jax._src.prng) ----------------
__host__ __device__ inline void tf2x32(uint32_t k0, uint32_t k1,
                                       uint32_t x0, uint32_t x1,
                                       uint32_t* o0, uint32_t* o1) {
  uint32_t ks2 = k0 ^ k1 ^ 0x1BD11BDAu;
  x0 += k0; x1 += k1;
#define TF_RND(r) { x0 += x1; x1 = (x1 << r) | (x1 >> (32 - r)); x1 ^= x0; }
  TF_RND(13) TF_RND(15) TF_RND(26) TF_RND(6)
  x0 += k1; x1 += ks2 + 1u;
  TF_RND(17) TF_RND(29) TF_RND(16) TF_RND(24)
  x0 += ks2; x1 += k0 + 2u;
  TF_RND(13) TF_RND(15) TF_RND(26) TF_RND(6)
  x0 += k0; x1 += k1 + 3u;
  TF_RND(17) TF_RND(29) TF_RND(16) TF_RND(24)
  x0 += k1; x1 += ks2 + 4u;
  TF_RND(13) TF_RND(15) TF_RND(26) TF_RND(6)
  x0 += ks2; x1 += k0 + 5u;
#undef TF_RND
  *o0 = x0; *o1 = x1;
}

// XLA ErfInv32 (Giles polynomial, w = -log1p(-x*x))
__device__ inline float erfinv_f32(float x) {
  float w = -log1pf(-x * x);
  float p;
  if (w < 5.0f) {
    w = w - 2.5f;
    p = 2.81022636e-08f;
    p = fmaf(p, w, 3.43273939e-07f);
    p = fmaf(p, w, -3.5233877e-06f);
    p = fmaf(p, w, -4.39150654e-06f);
    p = fmaf(p, w, 0.00021858087f);
    p = fmaf(p, w, -0.00125372503f);
    p = fmaf(p, w, -0.00417768164f);
    p = fmaf(p, w, 0.246640727f);
    p = fmaf(p, w, 1.50140941f);
  } else {
    w = sqrtf(w) - 3.0f;
    p = -0.000200214257f;
    p = fmaf(p, w, 0.000100950558f);
    p = fmaf(p, w, 0.00134934322f);
    p = fmaf(p, w, -0.00367342844f);
    p = fmaf(p, w, 0.00573950773f);
    p = fmaf(p, w, -0.0076224613f);
    p = fmaf(p, w, 0.00943887047f);
    p = fmaf(p, w, 1.00167406f);
    p = fmaf(p, w, 2.83297682f);
  }
  return p * x;
}

__device__ inline float noise_from_bits(uint32_t bits) {
  const float lo = -0.99999994f;            // nextafter(-1,0) in f32
  uint32_t fb = (bits >> 9) | 0x3f800000u;
  float f = __uint_as_float(fb) - 1.0f;     // [0,1)
  float u = fmaxf(lo, fmaf(f, 2.0f, lo));   // hi-lo rounds to exactly 2.0f
  return 0.1f * (1.41421354f * erfinv_f32(u));
}

__device__ inline float noise_elem(uint32_t fk0, uint32_t fk1, long t) {
  uint32_t o0, o1;
  tf2x32(fk0, fk1, (uint32_t)(((unsigned long)t) >> 32), (uint32_t)t, &o0, &o1);
  return noise_from_bits(o0 ^ o1);
}

// Detect int64 edge_index passed raw (odd int32 slots all-zero high words).
__device__ inline bool edges_are_i64(const int* __restrict__ ei) {
  return (ei[1] | ei[3] | ei[5] | ei[7] | ei[9] | ei[11] | ei[13] | ei[15]) == 0;
}

// ---------------- CSR build (bucketed; (chunk,band,row) segment order) ----------------
__global__ __launch_bounds__(256) void zero256_kernel(int* __restrict__ p) {
  p[threadIdx.x] = 0;
}

__global__ __launch_bounds__(256) void bucket_hist_kernel(const int* __restrict__ ei,
                                                          int* __restrict__ bucketCount,
                                                          long E, int shift) {
  __shared__ int cnt[256];
  int tid = threadIdx.x;
  cnt[tid] = 0;
  __syncthreads();
  long base = (long)blockIdx.x * (256 * FILLA_EPT);
  bool i64 = edges_are_i64(ei);
  #pragma unroll
  for (int j = 0; j < FILLA_EPT; ++j) {
    long e = base + tid + (long)j * 256;
    if (e < E) {
      int d = __builtin_nontemporal_load(&ei[i64 ? (2 * (E + e)) : (E + e)]);
      atomicAdd(&cnt[d >> shift], 1);
    }
  }
  __syncthreads();
  if (cnt[tid] > 0) atomicAdd(&bucketCount[tid], cnt[tid]);
}

__global__ __launch_bounds__(256) void bucket_scan_kernel(const int* __restrict__ bucketCount,
                                                          int* __restrict__ bucketBase,
                                                          int* __restrict__ bucketCursor,
                                                          int nb, int E) {
  __shared__ int lds[256];
  int tid = threadIdx.x;
  int v = (tid < nb) ? bucketCount[tid] : 0;
  lds[tid] = v;
  __syncthreads();
  for (int off = 1; off < 256; off <<= 1) {
    int t = (tid >= off) ? lds[tid - off] : 0;
    __syncthreads();
    lds[tid] += t;
    __syncthreads();
  }
  int excl = lds[tid] - v;
  if (tid < nb) { bucketBase[tid] = excl; bucketCursor[tid] = excl; }
  if (tid == 0) bucketBase[nb] = E;
}

// fillA: bin (src,dst) into coarse 512-row buckets in tmp (u64: dst<<32|src).
__global__ __launch_bounds__(256) void fillA_kernel(const int* __restrict__ ei,
                                                    int* __restrict__ bucketCursor,
                                                    uint64_t* __restrict__ tmp,
                                                    long E, int shift, int nb) {
  __shared__ int ldsCount[256];
  __shared__ int ldsBase[256];
  __shared__ int ldsRank[256];
  int tid = threadIdx.x;
  long base = (long)blockIdx.x * (256 * FILLA_EPT);
  bool i64 = edges_are_i64(ei);

  int sv[FILLA_EPT], dv[FILLA_EPT];
  ldsCount[tid] = 0; ldsRank[tid] = 0;
  __syncthreads();

  #pragma unroll
  for (int j = 0; j < FILLA_EPT; ++j) {
    long e = base + tid + (long)j * 256;
    if (e < E) {
      sv[j] = __builtin_nontemporal_load(&ei[i64 ? (2 * e) : e]);
      dv[j] = __builtin_nontemporal_load(&ei[i64 ? (2 * (E + e)) : (E + e)]);
      atomicAdd(&ldsCount[dv[j] >> shift], 1);
    } else { sv[j] = -1; dv[j] = -1; }
  }
  __syncthreads();
  if (tid < nb && ldsCount[tid] > 0)
    ldsBase[tid] = atomicAdd(&bucketCursor[tid], ldsCount[tid]);
  __syncthreads();
  #pragma unroll
  for (int j = 0; j < FILLA_EPT; ++j) {
    if (dv[j] >= 0) {
      int b = dv[j] >> shift;
      int r = atomicAdd(&ldsRank[b], 1);
      tmp[ldsBase[b] + r] = ((uint64_t)(uint32_t)dv[j] << 32) | (uint32_t)sv[j];
    }
  }
}

// fillB4: one wg per 512-row bucket. 8192-bin (chunk32,band16,row32) LDS
// histogram + scan -> boundary dump (bnd) + col scatter in segment order.
// Global segment order = (chunk, band, row); per-chunk data contiguous.
__global__ __launch_bounds__(256) void fillB4_kernel(const uint64_t* __restrict__ tmp,
                                                     const int* __restrict__ bucketBase,
                                                     int* __restrict__ bnd,
                                                     int* __restrict__ col,
                                                     int sb, int N, int nb, int NC) {
  __shared__ int h[8192];
  __shared__ int ps[256];
  int b = blockIdx.x;
  int tid = threadIdx.x;
  int r0 = b << 9;
  int beg = bucketBase[b], end = bucketBase[b + 1];

  for (int i = tid; i < 8192; i += 256) h[i] = 0;
  __syncthreads();
  for (int i = beg + tid; i < end; i += 256) {
    uint64_t e = __builtin_nontemporal_load(&tmp[i]);
    int r = (int)(e >> 32) - r0;
    uint32_t s = (uint32_t)e;
    int key = ((r >> 5) << 9) | ((int)(s >> sb) << 5) | (r & 31);
    atomicAdd(&h[key], 1);
  }
  __syncthreads();
  // exclusive scan over 8192 bins (thread owns 32 consecutive)
  int base_i = tid * 32;
  int sum = 0;
  #pragma unroll
  for (int j = 0; j < 32; ++j) sum += h[base_i + j];
  ps[tid] = sum;
  __syncthreads();
  for (int off = 1; off < 256; off <<= 1) {
    int t = (tid >= off) ? ps[tid - off] : 0;
    __syncthreads();
    ps[tid] += t;
    __syncthreads();
  }
  int run = ps[tid] - sum;
  #pragma unroll
  for (int j = 0; j < 32; ++j) { int c = h[base_i + j]; h[base_i + j] = run; run += c; }
  __syncthreads();
  // dump boundaries: bnd[b*8192 + i] = beg + prefix[i]
  for (int i = tid; i < 8192; i += 256) bnd[(size_t)b * 8192 + i] = beg + h[i];
  if (b == nb - 1 && tid == 0) bnd[(size_t)NC * 512] = end;  // sentinel
  __syncthreads();
  for (int i = beg + tid; i < end; i += 256) {
    uint64_t e = __builtin_nontemporal_load(&tmp[i]);
    int r = (int)(e >> 32) - r0;
    uint32_t s = (uint32_t)e;
    int key = ((r >> 5) << 9) | ((int)(s >> sb) << 5) | (r & 31);
    int slot = beg + atomicAdd(&h[key], 1);
    col[slot] = (int)s;
  }
}

// ---------------- hop 0: normalize x -> out[0] (f32, NT) + mirror (f16) ----------------
__global__ __launch_bounds__(256) void norm0_kernel(const float* __restrict__ in,
                                                    float* __restrict__ out,
                                                    __half* __restrict__ mir, int N) {
  long t = (long)blockIdx.x * blockDim.x + threadIdx.x;
  int row = (int)(t >> 6);
  int lane = (int)(t & 63);
  if (row >= N) return;
  float2 v = *(const float2*)(in + (size_t)row * D + lane * 2);
  float s = v.x * v.x + v.y * v.y;
  #pragma unroll
  for (int off = 32; off > 0; off >>= 1) s += __shfl_xor(s, off, 64);
  float inv = 1.0f / fmaxf(sqrtf(s), 1e-12f);
  f32x2 o; o.x = v.x * inv; o.y = v.y * inv;
  __builtin_nontemporal_store(o, (f32x2*)(out + (size_t)row * D + lane * 2));
  __half2 h = __float22half2_rn(make_float2(o.x, o.y));
  ((uint32_t*)mir)[(size_t)row * 64 + lane] = *(const uint32_t*)&h;
}

// ---------------- Band-synchronized register-tiled hop ----------------
// Wave owns 32 dst rows (acc in 64 VGPRs, static-indexed). Its edges are
// ordered (band, row): all resident waves walk 2MB src bands in lock-step,
// so band reads hit each XCD's 4MB L2. Epilogue stages acc through LDS so
// noise/normalize runs in a small runtime loop (static VGPR indexing kept).
__global__ __launch_bounds__(256) void gather_band(const __half* __restrict__ mirIn,
                                                   float* __restrict__ nxt,
                                                   __half* __restrict__ mirOut,
                                                   const int* __restrict__ bnd,
                                                   const int* __restrict__ col,
                                                   int NC, uint32_t fk0, uint32_t fk1) {
  __shared__ float2 stage[4][16][64];   // 32 KB
  int wl = threadIdx.x >> 6;
  int lane = threadIdx.x & 63;
  int c = blockIdx.x * 4 + wl;
  if (c >= NC) return;
  const int* bc = bnd + (size_t)c * 512;
  const uint32_t* mir32 = (const uint32_t*)mirIn;

  float2 acc[32];
  #pragma unroll
  for (int r = 0; r < 32; ++r) { acc[r].x = 0.f; acc[r].y = 0.f; }

  int cur = bc[0];
  for (int b = 0; b < 16; ++b) {
    #pragma unroll
    for (int r = 0; r < 32; ++r) {
      int seg_end = bc[b * 32 + r + 1];
      int i = cur;
      for (; i + 1 < seg_end; i += 2) {
        int s0 = col[i], s1 = col[i + 1];
        uint32_t u0 = mir32[(size_t)s0 * 64 + lane];
        uint32_t u1 = mir32[(size_t)s1 * 64 + lane];
        float2 f0 = __half22float2(*(const __half2*)&u0);
        float2 f1 = __half22float2(*(const __half2*)&u1);
        acc[r].x += f0.x + f1.x;
        acc[r].y += f0.y + f1.y;
      }
      if (i < seg_end) {
        int s0 = col[i];
        uint32_t u0 = mir32[(size_t)s0 * 64 + lane];
        float2 f0 = __half22float2(*(const __half2*)&u0);
        acc[r].x += f0.x;
        acc[r].y += f0.y;
      }
      cur = seg_end;
    }
  }

  long rowBase = (long)c * 32;
  #pragma unroll
  for (int ph = 0; ph < 2; ++ph) {
    #pragma unroll
    for (int r = 0; r < 16; ++r) stage[wl][r][lane] = acc[ph * 16 + r];
    // wave-private LDS region: no barrier needed, compiler inserts lgkmcnt
    for (int r = 0; r < 16; ++r) {
      float2 a = stage[wl][r][lane];
      long row = rowBase + ph * 16 + r;
      long t0 = row * D + 2 * lane;
      float a0 = a.x + noise_elem(fk0, fk1, t0);
      float a1 = a.y + noise_elem(fk0, fk1, t0 + 1);
      float ss = a0 * a0 + a1 * a1;
      #pragma unroll
      for (int off = 32; off > 0; off >>= 1) ss += __shfl_xor(ss, off, 64);
      float inv = 1.0f / fmaxf(sqrtf(ss), 1e-12f);
      a0 *= inv; a1 *= inv;
      f32x2 o; o.x = a0; o.y = a1;
      __builtin_nontemporal_store(o, (f32x2*)(nxt + row * D + 2 * lane));
      __half2 h = __float22half2_rn(make_float2(a0, a1));
      __builtin_nontemporal_store(*(const uint32_t*)&h,
                                  (uint32_t*)mirOut + row * 64 + lane);
    }
  }
}

// ---------------- Fallback kernels (round-3 atomic path, proven) ----------------
__global__ __launch_bounds__(256) void noise_kernel(float* __restrict__ out,
                                                    uint32_t fk0, uint32_t fk1, long n) {
  long t = (long)blockIdx.x * blockDim.x + threadIdx.x;
  if (t >= n) return;
  out[t] = noise_elem(fk0, fk1, t);
}

__global__ __launch_bounds__(256) void scatter_kernel(const float* __restrict__ cur,
                                                      float* __restrict__ aggr,
                                                      const int* __restrict__ ei, long E) {
  long tid = (long)blockIdx.x * blockDim.x + threadIdx.x;
  long e = tid >> 5;
  if (e >= E) return;
  int lane = (int)(tid & 31);
  bool i64 = edges_are_i64(ei);
  int s = ei[i64 ? (2 * e) : e];
  int d = ei[i64 ? (2 * (E + e)) : (E + e)];
  float4 v = *(const float4*)(cur + (size_t)s * D + lane * 4);
  float* dp = aggr + (size_t)d * D + lane * 4;
  unsafeAtomicAdd(dp + 0, v.x);
  unsafeAtomicAdd(dp + 1, v.y);
  unsafeAtomicAdd(dp + 2, v.z);
  unsafeAtomicAdd(dp + 3, v.w);
}

__global__ __launch_bounds__(256) void norm_kernel(const float* __restrict__ in,
                                                   float* __restrict__ out, int N) {
  long t = (long)blockIdx.x * blockDim.x + threadIdx.x;
  int row = (int)(t >> 6);
  int lane = (int)(t & 63);
  if (row >= N) return;
  float2 v = *(const float2*)(in + (size_t)row * D + lane * 2);
  float s = v.x * v.x + v.y * v.y;
  #pragma unroll
  for (int off = 32; off > 0; off >>= 1) s += __shfl_xor(s, off, 64);
  float inv = 1.0f / fmaxf(sqrtf(s), 1e-12f);
  float2 o; o.x = v.x * inv; o.y = v.y * inv;
  *(float2*)(out + (size_t)row * D + lane * 2) = o;
}

static inline size_t align_up(size_t v, size_t a) { return (v + a - 1) & ~(a - 1); }

extern "C" void kernel_launch(void* const* d_in, const int* in_sizes, int n_in,
                              void* d_out, int out_size, void* d_ws, size_t ws_size,
                              hipStream_t stream) {
  const float* x = (const float*)d_in[0];
  const int* ei = (const int*)d_in[1];
  const long N = in_sizes[0] / D;      // 100000
  const long E = in_sizes[1] / 2;      // 3200000
  float* out = (float*)d_out;
  const long ND = N * D;

  uint32_t fk0[NUM_HOPS], fk1[NUM_HOPS];
  for (int k = 0; k < NUM_HOPS; ++k)
    tf2x32(0u, 42u, 0u, (uint32_t)k, &fk0[k], &fk1[k]);

  // geometry: 512-row buckets (shift must be exactly 9 for fillB4), nb <= 256
  int shift = 9;
  while ((((N + ((long)1 << shift) - 1) >> shift)) > 256) shift++;
  const int nb = (int)((N + ((long)1 << shift) - 1) >> shift);
  // 16 src bands: band = src >> sb in [0,16)
  int sb = 0;
  while ((((long)N - 1) >> sb) > 15) sb++;
  const int NC = (int)(N / 32);        // 32-row chunks (one per wave)

  // Aligned workspace carve-out
  uintptr_t base = (uintptr_t)d_ws;
  size_t off = 0;
  auto carve = [&](size_t bytes, size_t align) -> uintptr_t {
    off = align_up(off, align);
    uintptr_t p = base + off;
    off += bytes;
    return p;
  };
  int* bucketCount  = (int*)carve(256 * 4, 256);
  int* bucketBase   = (int*)carve((size_t)(nb + 1) * 4, 256);
  int* bucketCursor = (int*)carve((size_t)nb * 4, 256);
  int* bnd          = (int*)carve(((size_t)nb * 8192 + 1) * 4, 256);
  int* col          = (int*)carve((size_t)E * 4, 256);
  uint64_t* tmp     = (uint64_t*)carve((size_t)E * 8, 256);
  __half* mirA      = (__half*)carve((size_t)ND * 2, 256);
  __half* mirB      = (__half*)carve((size_t)ND * 2, 256);
  size_t need_full = off;

  long nthreads = N * 64;
  int ngrid = (int)((nthreads + 255) / 256);

  if (ws_size >= need_full && shift == 9 && nb <= 256 && (N % 32) == 0) {
    long epw = 256L * FILLA_EPT;
    int nblk = (int)((E + epw - 1) / epw);
    zero256_kernel<<<1, 256, 0, stream>>>(bucketCount);
    bucket_hist_kernel<<<nblk, 256, 0, stream>>>(ei, bucketCount, E, shift);
    bucket_scan_kernel<<<1, 256, 0, stream>>>(bucketCount, bucketBase, bucketCursor, nb, (int)E);
    fillA_kernel<<<nblk, 256, 0, stream>>>(ei, bucketCursor, tmp, E, shift, nb);
    fillB4_kernel<<<nb, 256, 0, stream>>>(tmp, bucketBase, bnd, col, sb, (int)N, nb, NC);

    norm0_kernel<<<ngrid, 256, 0, stream>>>(x, out, mirA, (int)N);
    int ggrid = (NC + 3) / 4;
    for (int k = 0; k < NUM_HOPS; ++k) {
      float* nxt = out + (size_t)(k + 1) * ND;
      const __half* mi = (k & 1) ? mirB : mirA;
      __half* mo       = (k & 1) ? mirA : mirB;
      gather_band<<<ggrid, 256, 0, stream>>>(mi, nxt, mo, bnd, col,
                                             NC, fk0[k], fk1[k]);
    }
  } else {
    // Fallback: proven round-3 atomic path
    norm_kernel<<<ngrid, 256, 0, stream>>>(x, out, (int)N);
    for (int k = 0; k < NUM_HOPS; ++k) {
      const float* cur = out + (size_t)k * ND;
      float* nxt = out + (size_t)(k + 1) * ND;
      noise_kernel<<<(int)((ND + 255) / 256), 256, 0, stream>>>(nxt, fk0[k], fk1[k], ND);
      long sthreads = E * 32;
      scatter_kernel<<<(int)((sthreads + 255) / 256), 256, 0, stream>>>(cur, nxt, ei, E);
      norm_kernel<<<ngrid, 256, 0, stream>>>(nxt, nxt, (int)N);
    }
  }
}